// Round 1
// baseline (105.138 us; speedup 1.0000x reference)
//
#include <hip/hip_runtime.h>
#include <math.h>

#define HF 96
#define WF 192
#define CC 32
#define NPIX (HF*WF)     // 18432
#define DFULL 192
#define DQ 48
#define HO 384
#define WO 768

// Kernel A: per-pixel inverse L2 norm over channels for both images.
// inv[0:NPIX) = left, inv[NPIX:2*NPIX) = right
__global__ __launch_bounds__(256) void knorm(const float* __restrict__ L,
                                             const float* __restrict__ R,
                                             float* __restrict__ inv) {
    int pid = blockIdx.x * 256 + threadIdx.x;
    if (pid >= 2 * NPIX) return;
    const float* p = (pid < NPIX) ? L : R;
    int off = (pid < NPIX) ? pid : pid - NPIX;
    float s = 0.0f;
    #pragma unroll
    for (int c = 0; c < CC; ++c) {
        float v = p[c * NPIX + off];
        s = fmaf(v, v, s);
    }
    inv[pid] = 1.0f / sqrtf(s + 1e-12f);
}

// Kernel B: cost volume. One block per (row h, d-chunk of 48).
// cost[d][h][w] = dot_c( Lnorm[:,h,w], Rnorm[:,h,w-d] ), 0 if w<d.
__global__ __launch_bounds__(192) void kcost(const float* __restrict__ L,
                                             const float* __restrict__ R,
                                             const float* __restrict__ inv,
                                             float* __restrict__ out) {
    __shared__ __align__(16) float rs[WF * 36];   // padded stride 36 floats (144B, 16B-aligned)
    const int h  = blockIdx.x;
    const int d0 = blockIdx.y * 48;
    const int tid = threadIdx.x;

    // stage normalized right row into LDS: rs[w*36 + c]
    for (int i = tid; i < WF * CC; i += 192) {
        int c = i / WF;
        int w = i - c * WF;
        rs[w * 36 + c] = R[c * NPIX + h * WF + w] * inv[NPIX + h * WF + w];
    }

    // normalized left pixel (this thread's w) into registers
    const int w = tid;
    float lreg[CC];
    {
        float invl = inv[h * WF + w];
        #pragma unroll
        for (int c = 0; c < CC; ++c)
            lreg[c] = L[c * NPIX + h * WF + w] * invl;
    }
    __syncthreads();

    for (int dd = 0; dd < 48; ++dd) {
        int d = d0 + dd;
        int wp = w - d;
        float acc = 0.0f;
        if (wp >= 0) {
            const float* r = &rs[wp * 36];
            #pragma unroll
            for (int c = 0; c < CC; ++c)
                acc = fmaf(lreg[c], r[c], acc);
        }
        out[(d * HF + h) * WF + w] = acc;
    }
}

// Kernel C: trilinear upsample (4x in d,h,w) of cost[0:48] + argmax over d + max(.,1).
__global__ __launch_bounds__(256) void kpred(const float* __restrict__ cost,
                                             float* __restrict__ pred) {
    int pid = blockIdx.x * 256 + threadIdx.x;
    if (pid >= HO * WO) return;
    int w = pid % WO;
    int h = pid / WO;

    // h interpolation: src = (h+0.5)/4 - 0.5 = (2h-3)/8, exact in fp32
    float sh = (float)(2 * h - 3) * 0.125f;
    float fh = sh - floorf(sh);
    int h0 = (int)floorf(sh);
    int h1 = h0 + 1;
    if (h0 < 0)      { h0 = 0;      h1 = 0;      fh = 0.0f; }  // weights fold to 1.0 on edge
    if (h1 > HF - 1) { h1 = HF - 1;              fh = 0.0f; }  // h0 == HF-1 here

    float sw = (float)(2 * w - 3) * 0.125f;
    float fw = sw - floorf(sw);
    int w0 = (int)floorf(sw);
    int w1 = w0 + 1;
    if (w0 < 0)      { w0 = 0;      w1 = 0;      fw = 0.0f; }
    if (w1 > WF - 1) { w1 = WF - 1;              fw = 0.0f; }

    const float wh0 = 1.0f - fh, wh1 = fh;
    const float ww0 = 1.0f - fw, ww1 = fw;

    const int i00 = h0 * WF + w0;
    const int i10 = h1 * WF + w0;
    const int i01 = h0 * WF + w1;
    const int i11 = h1 * WF + w1;

    // bilinear at depth slice k (h contracted first, then w — matches ref dim order h,w)
    auto bilin = [&](int k) -> float {
        const float* s = cost + k * NPIX;
        float v00 = s[i00], v10 = s[i10], v01 = s[i01], v11 = s[i11];
        float a0 = fmaf(wh1, v10, wh0 * v00);
        float a1 = fmaf(wh1, v11, wh0 * v01);
        return fmaf(ww1, a1, ww0 * a0);
    };

    // d_out = 0,1 fold exactly to slice 0 -> candidate index 0 (tie -> first index)
    float bprev = bilin(0);
    float best = bprev;
    int bidx = 0;

    for (int k = 1; k < DQ; ++k) {
        float b = bilin(k);
        // d_out = 4k-2 .. 4k+1, fracs 1/8, 3/8, 5/8, 7/8 (exact weights)
        #pragma unroll
        for (int t = 0; t < 4; ++t) {
            float f = 0.125f + 0.25f * (float)t;
            float v = fmaf(f, b, (1.0f - f) * bprev);
            if (v > best) { best = v; bidx = 4 * k - 2 + t; }
        }
        bprev = b;
    }
    // d_out = 190,191 fold exactly to slice 47 -> candidate index 190
    if (bprev > best) { best = bprev; bidx = 190; }

    pred[pid] = (float)(bidx < 1 ? 1 : bidx);
}

extern "C" void kernel_launch(void* const* d_in, const int* in_sizes, int n_in,
                              void* d_out, int out_size, void* d_ws, size_t ws_size,
                              hipStream_t stream) {
    const float* L = (const float*)d_in[0];
    const float* R = (const float*)d_in[1];
    float* out = (float*)d_out;                 // cost_init: [192][96][192]
    float* pred = out + DFULL * NPIX;           // pred: [384][768]
    float* inv = (float*)d_ws;                  // 2*18432 floats

    knorm<<<(2 * NPIX + 255) / 256, 256, 0, stream>>>(L, R, inv);
    kcost<<<dim3(HF, 4), 192, 0, stream>>>(L, R, inv, out);
    kpred<<<(HO * WO + 255) / 256, 256, 0, stream>>>(out, pred);
}

// Round 2
// 102.574 us; speedup vs baseline: 1.0250x; 1.0250x over previous
//
#include <hip/hip_runtime.h>
#include <math.h>

#define HF 96
#define WF 192
#define CC 32
#define NPIX (HF*WF)     // 18432
#define DFULL 192
#define DQ 48
#define HO 384
#define WO 768

// Cost volume with fused L2 normalization.
// Block = (h, y): 192 threads (one per w). Handles d = 4*dd + y, dd in [0,48)
// (interleaved d-assignment balances the w<d masked region across blocks).
// LDS layout rs[c*192 + w]: at fixed c, lanes read consecutive w-d -> consecutive
// banks (192 % 32 == 0), 2 lanes/bank = conflict-free (m136).
__global__ __launch_bounds__(192) void kcost(const float* __restrict__ L,
                                             const float* __restrict__ R,
                                             float* __restrict__ out) {
    __shared__ float rs[CC * WF];   // 24 KB
    const int h = blockIdx.x;
    const int y = blockIdx.y;
    const int w = threadIdx.x;

    // stage right pixel w: thread owns all 32 channels -> in-register norm
    {
        float rreg[CC];
        float s = 0.0f;
        #pragma unroll
        for (int c = 0; c < CC; ++c) {
            float v = R[c * NPIX + h * WF + w];
            rreg[c] = v;
            s = fmaf(v, v, s);
        }
        float rinv = 1.0f / sqrtf(s + 1e-12f);
        #pragma unroll
        for (int c = 0; c < CC; ++c)
            rs[c * WF + w] = rreg[c] * rinv;
    }

    // left pixel (this thread's w), normalized, in registers
    float lreg[CC];
    {
        float s = 0.0f;
        #pragma unroll
        for (int c = 0; c < CC; ++c) {
            float v = L[c * NPIX + h * WF + w];
            lreg[c] = v;
            s = fmaf(v, v, s);
        }
        float linv = 1.0f / sqrtf(s + 1e-12f);
        #pragma unroll
        for (int c = 0; c < CC; ++c) lreg[c] *= linv;
    }

    __syncthreads();

    for (int dd = 0; dd < 48; ++dd) {
        int d = 4 * dd + y;
        int wp = w - d;
        float acc = 0.0f;
        if (wp >= 0) {
            #pragma unroll
            for (int c = 0; c < CC; ++c)
                acc = fmaf(lreg[c], rs[c * WF + wp], acc);
        }
        out[(d * HF + h) * WF + w] = acc;   // coalesced per d
    }
}

// Trilinear upsample (4x in d,h,w) of cost[0:48] + argmax over d + max(.,1).
__global__ __launch_bounds__(256) void kpred(const float* __restrict__ cost,
                                             float* __restrict__ pred) {
    int pid = blockIdx.x * 256 + threadIdx.x;
    if (pid >= HO * WO) return;
    int w = pid % WO;
    int h = pid / WO;

    // src coord = (x+0.5)/4 - 0.5 = (2x-3)/8, exact in fp32
    float sh = (float)(2 * h - 3) * 0.125f;
    float fh = sh - floorf(sh);
    int h0 = (int)floorf(sh);
    int h1 = h0 + 1;
    if (h0 < 0)      { h0 = 0; h1 = 0; fh = 0.0f; }   // clamped weights renormalize to exactly 1
    if (h1 > HF - 1) { h1 = HF - 1;    fh = 0.0f; }

    float sw = (float)(2 * w - 3) * 0.125f;
    float fw = sw - floorf(sw);
    int w0 = (int)floorf(sw);
    int w1 = w0 + 1;
    if (w0 < 0)      { w0 = 0; w1 = 0; fw = 0.0f; }
    if (w1 > WF - 1) { w1 = WF - 1;    fw = 0.0f; }

    const float wh0 = 1.0f - fh, wh1 = fh;
    const float ww0 = 1.0f - fw, ww1 = fw;

    const int i00 = h0 * WF + w0;
    const int i10 = h1 * WF + w0;
    const int i01 = h0 * WF + w1;
    const int i11 = h1 * WF + w1;

    auto bilin = [&](int k) -> float {
        const float* s = cost + k * NPIX;
        float v00 = s[i00], v10 = s[i10], v01 = s[i01], v11 = s[i11];
        float a0 = fmaf(wh1, v10, wh0 * v00);
        float a1 = fmaf(wh1, v11, wh0 * v01);
        return fmaf(ww1, a1, ww0 * a0);
    };

    // d_out = 0,1 fold exactly to slice 0 (ties -> first index)
    float bprev = bilin(0);
    float best = bprev;
    int bidx = 0;

    for (int k = 1; k < DQ; ++k) {
        float b = bilin(k);
        #pragma unroll
        for (int t = 0; t < 4; ++t) {           // d_out = 4k-2 .. 4k+1, fracs 1/8..7/8
            float f = 0.125f + 0.25f * (float)t;
            float v = fmaf(f, b, (1.0f - f) * bprev);
            if (v > best) { best = v; bidx = 4 * k - 2 + t; }
        }
        bprev = b;
    }
    if (bprev > best) { best = bprev; bidx = 190; }  // d_out = 190,191 fold to slice 47

    pred[pid] = (float)(bidx < 1 ? 1 : bidx);
}

extern "C" void kernel_launch(void* const* d_in, const int* in_sizes, int n_in,
                              void* d_out, int out_size, void* d_ws, size_t ws_size,
                              hipStream_t stream) {
    const float* L = (const float*)d_in[0];
    const float* R = (const float*)d_in[1];
    float* out = (float*)d_out;                 // cost_init: [192][96][192]
    float* pred = out + DFULL * NPIX;           // pred: [384][768]

    kcost<<<dim3(HF, 4), 192, 0, stream>>>(L, R, out);
    kpred<<<(HO * WO + 255) / 256, 256, 0, stream>>>(out, pred);
}

// Round 3
// 99.022 us; speedup vs baseline: 1.0618x; 1.0359x over previous
//
#include <hip/hip_runtime.h>
#include <math.h>

#define HF 96
#define WF 192
#define CC 32
#define NPIX (HF*WF)     // 18432
#define DFULL 192
#define DQ 48
#define HO 384
#define WO 768
#define SR 200           // R row stride in LDS: 4 zero-guard floats + 192 + 4 pad

// Cost volume, fused L2 norm, 4x4 (w,d) register tiles.
// Grid (96 rows, 5 tile-chunks), 256 threads. Tiles enumerated so consecutive
// threads share dt and ascend wt -> b128 LDS reads stride 16B (conflict-free)
// and float4 stores coalesce. Zero guard Rb[c][0..3]=0 makes diagonal tiles'
// w<d outputs exactly 0; strict-upper tiles zero-filled by mirror threads.
__global__ __launch_bounds__(256) void kcost(const float* __restrict__ L,
                                             const float* __restrict__ R,
                                             float* __restrict__ out) {
    __shared__ __align__(16) float Ls[CC * WF];   // 24.0 KB, Lnorm[c][w]
    __shared__ __align__(16) float Rb[CC * SR];   // 25.0 KB, Rnorm[c][w-4] (guarded)
    const int h = blockIdx.x;
    const int tid = threadIdx.x;

    // zero guard at head of each R row
    for (int i = tid; i < CC * 4; i += 256) Rb[(i >> 2) * SR + (i & 3)] = 0.0f;

    if (tid < WF) {
        const int w = tid;
        float lr[CC], rr[CC];
        float sl = 0.0f, sr = 0.0f;
        #pragma unroll
        for (int c = 0; c < CC; ++c) {
            float lv = L[c * NPIX + h * WF + w];
            float rv = R[c * NPIX + h * WF + w];
            lr[c] = lv; rr[c] = rv;
            sl = fmaf(lv, lv, sl);
            sr = fmaf(rv, rv, sr);
        }
        const float il = 1.0f / sqrtf(sl + 1e-12f);
        const float ir = 1.0f / sqrtf(sr + 1e-12f);
        #pragma unroll
        for (int c = 0; c < CC; ++c) {
            Ls[c * WF + w] = lr[c] * il;
            Rb[c * SR + 4 + w] = rr[c] * ir;
        }
    }
    __syncthreads();

    const int t = blockIdx.y * 256 + tid;
    if (t >= 1176) return;

    // reversed-triangle decode: u=1175-t -> (wu,du) lower-tri; wt=47-du, dt=47-wu
    // => consecutive t: same dt, wt ascending.
    const int u = 1175 - t;
    int wu = (int)((sqrtf(8.0f * (float)u + 1.0f) - 1.0f) * 0.5f);
    while ((wu + 1) * (wu + 2) / 2 <= u) ++wu;
    while (wu * (wu + 1) / 2 > u) --wu;
    const int du = u - wu * (wu + 1) / 2;
    const int wt = 47 - du;
    const int dt = 47 - wu;

    const int w0 = wt * 4, d0 = dt * 4;
    const int base = w0 - d0;           // >= 0, multiple of 4

    float a00=0,a01=0,a02=0,a03=0;      // a[j][i], j = d offset, i = w offset
    float a10=0,a11=0,a12=0,a13=0;
    float a20=0,a21=0,a22=0,a23=0;
    float a30=0,a31=0,a32=0,a33=0;

    #pragma unroll 4
    for (int c = 0; c < CC; ++c) {
        const float4 lv = *(const float4*)&Ls[c * WF + w0];
        const float4 r0 = *(const float4*)&Rb[c * SR + base];      // Rn[base-4..base-1]
        const float4 r1 = *(const float4*)&Rb[c * SR + base + 4];  // Rn[base..base+3]
        // output (i,j) uses Rn[base + i - j]
        a00 = fmaf(lv.x, r1.x, a00); a01 = fmaf(lv.y, r1.y, a01);
        a02 = fmaf(lv.z, r1.z, a02); a03 = fmaf(lv.w, r1.w, a03);
        a10 = fmaf(lv.x, r0.w, a10); a11 = fmaf(lv.y, r1.x, a11);
        a12 = fmaf(lv.z, r1.y, a12); a13 = fmaf(lv.w, r1.z, a13);
        a20 = fmaf(lv.x, r0.z, a20); a21 = fmaf(lv.y, r0.w, a21);
        a22 = fmaf(lv.z, r1.x, a22); a23 = fmaf(lv.w, r1.y, a23);
        a30 = fmaf(lv.x, r0.y, a30); a31 = fmaf(lv.y, r0.z, a31);
        a32 = fmaf(lv.z, r0.w, a32); a33 = fmaf(lv.w, r1.x, a33);
    }

    {
        float4 v;
        v.x=a00; v.y=a01; v.z=a02; v.w=a03;
        *(float4*)&out[(d0 + 0) * NPIX + h * WF + w0] = v;
        v.x=a10; v.y=a11; v.z=a12; v.w=a13;
        *(float4*)&out[(d0 + 1) * NPIX + h * WF + w0] = v;
        v.x=a20; v.y=a21; v.z=a22; v.w=a23;
        *(float4*)&out[(d0 + 2) * NPIX + h * WF + w0] = v;
        v.x=a30; v.y=a31; v.z=a32; v.w=a33;
        *(float4*)&out[(d0 + 3) * NPIX + h * WF + w0] = v;
    }

    if (wt > dt) {
        // zero the mirrored strict-upper tile: a = wt-dt-1, b = 47-dt (a < b)
        const int za = (wt - dt - 1) * 4;
        const int zb = (47 - dt) * 4;
        const float4 z = {0.0f, 0.0f, 0.0f, 0.0f};
        #pragma unroll
        for (int j = 0; j < 4; ++j)
            *(float4*)&out[(zb + j) * NPIX + h * WF + za] = z;
    }
}

// Trilinear upsample + argmax. Thread = (h_out, m): 4 output w's {4m+2..4m+5}
// share source cols (m, m+1) -> 4 loads per k serve 4 pixels. Piecewise-linear
// d-interp: per segment evaluate only the max-end sample (same fma formula).
__global__ __launch_bounds__(256) void kpred(const float* __restrict__ cost,
                                             float* __restrict__ pred) {
    const int mIdx = blockIdx.x * 64 + threadIdx.x;  // 0..255; valid <= 192
    const int h = blockIdx.y * 4 + threadIdx.y;
    if (mIdx > 192) return;
    const int m = mIdx - 1;

    float sh = (float)(2 * h - 3) * 0.125f;
    float fh = sh - floorf(sh);
    int h0 = (int)floorf(sh);
    int h1 = h0 + 1;
    if (h0 < 0)      { h0 = 0; h1 = 0; fh = 0.0f; }
    if (h1 > HF - 1) { h1 = HF - 1;    fh = 0.0f; }
    const float wh0 = 1.0f - fh, wh1 = fh;

    const bool edge = (m < 0) || (m >= WF - 1);
    const int w0 = (m < 0) ? 0 : ((m >= WF - 1) ? WF - 1 : m);
    const int w1 = (m < 0) ? 0 : ((m >= WF - 1) ? WF - 1 : m + 1);

    float fr[4];
    #pragma unroll
    for (int r = 0; r < 4; ++r) fr[r] = edge ? 0.0f : (0.125f + 0.25f * (float)r);

    const int i00 = h0 * WF + w0;
    const int i10 = h1 * WF + w0;
    const int i01 = h0 * WF + w1;
    const int i11 = h1 * WF + w1;

    float bp[4], best[4];
    int bi[4];
    {
        const float* s = cost;
        float q00 = s[i00], q10 = s[i10], q01 = s[i01], q11 = s[i11];
        float A0 = fmaf(wh1, q10, wh0 * q00);
        float A1 = fmaf(wh1, q11, wh0 * q01);
        #pragma unroll
        for (int r = 0; r < 4; ++r) {
            bp[r] = fmaf(fr[r], A1, (1.0f - fr[r]) * A0);
            best[r] = bp[r];
            bi[r] = 0;
        }
    }

    for (int k = 1; k < DQ; ++k) {
        const float* s = cost + k * NPIX;
        float q00 = s[i00], q10 = s[i10], q01 = s[i01], q11 = s[i11];
        float A0 = fmaf(wh1, q10, wh0 * q00);
        float A1 = fmaf(wh1, q11, wh0 * q01);
        #pragma unroll
        for (int r = 0; r < 4; ++r) {
            float b = fmaf(fr[r], A1, (1.0f - fr[r]) * A0);
            float cand; int ci;
            if (b > bp[r]) { cand = fmaf(0.875f, b, 0.125f * bp[r]); ci = 4 * k + 1; }
            else           { cand = fmaf(0.125f, b, 0.875f * bp[r]); ci = 4 * k - 2; }
            if (cand > best[r]) { best[r] = cand; bi[r] = ci; }
            bp[r] = b;
        }
    }
    #pragma unroll
    for (int r = 0; r < 4; ++r)
        if (bp[r] > best[r]) bi[r] = 190;      // d_out = 190,191 fold to slice 47

    float v[4];
    #pragma unroll
    for (int r = 0; r < 4; ++r) v[r] = (float)(bi[r] < 1 ? 1 : bi[r]);

    float* prow = pred + h * WO;
    if (m < 0) {
        float2 o; o.x = v[0]; o.y = v[0];
        *(float2*)&prow[0] = o;                 // w_out 0,1 = col 0
    } else if (m >= WF - 1) {
        float2 o; o.x = v[0]; o.y = v[0];
        *(float2*)&prow[WO - 2] = o;            // w_out 766,767 = col 191
    } else {
        float2 o0; o0.x = v[0]; o0.y = v[1];
        float2 o1; o1.x = v[2]; o1.y = v[3];
        *(float2*)&prow[4 * m + 2] = o0;
        *(float2*)&prow[4 * m + 4] = o1;
    }
}

extern "C" void kernel_launch(void* const* d_in, const int* in_sizes, int n_in,
                              void* d_out, int out_size, void* d_ws, size_t ws_size,
                              hipStream_t stream) {
    const float* L = (const float*)d_in[0];
    const float* R = (const float*)d_in[1];
    float* out = (float*)d_out;                 // cost_init: [192][96][192]
    float* pred = out + DFULL * NPIX;           // pred: [384][768]

    kcost<<<dim3(HF, 5), 256, 0, stream>>>(L, R, out);
    kpred<<<dim3(4, HF), dim3(64, 4), 0, stream>>>(out, pred);
}